// Round 9
// baseline (111.434 us; speedup 1.0000x reference)
//
#include <hip/hip_runtime.h>
#include <stdint.h>
#include <stddef.h>

typedef __attribute__((ext_vector_type(8))) short bf16x8;
typedef __attribute__((ext_vector_type(4))) float f32x4;

#define NROWS 400000
#define KC 128
#define DIMS 64
#define NTILES (NROWS / 16)

__device__ __forceinline__ short f2bf(float f) {
    union { float f; uint32_t u; } v; v.f = f;
    uint32_t u = v.u;
    uint32_t r = (u + 0x7FFFu + ((u >> 16) & 1u)) >> 16;  // RNE, finite inputs
    return (short)r;
}

__device__ __forceinline__ float frcp(float x) { return __builtin_amdgcn_rcpf(x); }

// Stage -2*centers bf16 fragments (A-operand) into LDS + center norms into cnLDS.
__device__ __forceinline__ void stage_centers_T(
        const float* __restrict__ centers, bf16x8 (*blds)[2][64],
        float* cnLDS, int wid, int lane, int m, int g)
{
    #pragma unroll
    for (int cb = 0; cb < 8; ++cb) {
        float cacc = 0.f;
        bf16x8 bfr[2];
        #pragma unroll
        for (int h = 0; h < 2; ++h) {
            const float* src = centers + (size_t)(cb * 16 + m) * DIMS + h * 32 + g * 8;
            f32x4 c0 = *(const f32x4*)src;
            f32x4 c1 = *(const f32x4*)(src + 4);
            bf16x8 b;
            #pragma unroll
            for (int j = 0; j < 4; ++j) {
                float f0 = c0[j], f1 = c1[j];
                cacc += f0 * f0 + f1 * f1;
                b[j]     = f2bf(-2.0f * f0);
                b[j + 4] = f2bf(-2.0f * f1);
            }
            bfr[h] = b;
        }
        cacc += __shfl_xor(cacc, 16);
        cacc += __shfl_xor(cacc, 32);
        if (wid == 0) {
            blds[cb][0][lane] = bfr[0];
            blds[cb][1][lane] = bfr[1];
            if (g == 0) cnLDS[cb * 16 + m] = cacc;
        }
    }
    __syncthreads();
}

// K1: embeds -> q (written once) + colsum partials. Transposed MFMA D[k][n].
__global__ __launch_bounds__(256) void k1_q_colsum(
        const float* __restrict__ embeds, const float* __restrict__ centers,
        float* __restrict__ q, float* __restrict__ colsum_part, int nblocks)
{
    __shared__ bf16x8 blds[8][2][64];
    __shared__ float cnLDS[128];
    __shared__ float cl[4 * 128];
    const int tid = threadIdx.x, wid = tid >> 6, lane = tid & 63;
    const int m = lane & 15, g = lane >> 4;

    stage_centers_T(centers, blds, cnLDS, wid, lane, m, g);

    f32x4 cnr[8];
    #pragma unroll
    for (int cb = 0; cb < 8; ++cb) cnr[cb] = *(const f32x4*)&cnLDS[cb * 16 + g * 4];

    float csum[8][4];
    #pragma unroll
    for (int cb = 0; cb < 8; ++cb)
        #pragma unroll
        for (int r = 0; r < 4; ++r) csum[cb][r] = 0.f;

    const int gwid = blockIdx.x * 4 + wid;
    const int nw = nblocks * 4;

    int t = gwid;
    f32x4 n0, n1, n2, n3;
    if (t < NTILES) {
        const float* src = embeds + (size_t)(t * 16 + m) * DIMS + g * 8;
        n0 = *(const f32x4*)src;       n1 = *(const f32x4*)(src + 4);
        n2 = *(const f32x4*)(src + 32); n3 = *(const f32x4*)(src + 36);
    }
    for (; t < NTILES; t += nw) {
        f32x4 c0 = n0, c1 = n1, c2 = n2, c3 = n3;
        int tn = t + nw;
        if (tn < NTILES) {
            const float* src = embeds + (size_t)(tn * 16 + m) * DIMS + g * 8;
            n0 = *(const f32x4*)src;       n1 = *(const f32x4*)(src + 4);
            n2 = *(const f32x4*)(src + 32); n3 = *(const f32x4*)(src + 36);
        }
        bf16x8 a0, a1;
        float en = 0.f;
        #pragma unroll
        for (int j = 0; j < 4; ++j) {
            float f0 = c0[j], f1 = c1[j], f2 = c2[j], f3 = c3[j];
            en += f0 * f0 + f1 * f1 + f2 * f2 + f3 * f3;
            a0[j] = f2bf(f0); a0[j + 4] = f2bf(f1);
            a1[j] = f2bf(f2); a1[j + 4] = f2bf(f3);
        }
        en += __shfl_xor(en, 16);
        en += __shfl_xor(en, 32);

        f32x4 acc[8];
        #pragma unroll
        for (int cb = 0; cb < 8; ++cb) {
            f32x4 a;
            #pragma unroll
            for (int r = 0; r < 4; ++r) a[r] = cnr[cb][r] + en;
            a = __builtin_amdgcn_mfma_f32_16x16x32_bf16(blds[cb][0][lane], a0, a, 0, 0, 0);
            a = __builtin_amdgcn_mfma_f32_16x16x32_bf16(blds[cb][1][lane], a1, a, 0, 0, 0);
            acc[cb] = a;   // sq[k][n]
        }

        float rsp = 0.f;
        #pragma unroll
        for (int cb = 0; cb < 8; ++cb)
            #pragma unroll
            for (int r = 0; r < 4; ++r) {
                float dist = frcp(1.0f + fmaxf(acc[cb][r], 0.f));
                acc[cb][r] = dist;
                rsp += dist;
            }
        rsp += __shfl_xor(rsp, 16);
        rsp += __shfl_xor(rsp, 32);
        float invR = frcp(rsp);

        float* qrow = q + (size_t)(t * 16 + m) * KC + g * 4;
        #pragma unroll
        for (int cb = 0; cb < 8; ++cb)
            #pragma unroll
            for (int r = 0; r < 4; ++r) {
                float qv = acc[cb][r] * invR;
                qrow[cb * 16 + r] = qv;
                csum[cb][r] += qv;
            }
    }

    // butterfly over m-lanes: colsum for k = cb*16 + 4g + r
    #pragma unroll
    for (int cb = 0; cb < 8; ++cb)
        #pragma unroll
        for (int r = 0; r < 4; ++r) {
            float v = csum[cb][r];
            v += __shfl_xor(v, 1); v += __shfl_xor(v, 2);
            v += __shfl_xor(v, 4); v += __shfl_xor(v, 8);
            csum[cb][r] = v;
        }
    if (m == 0) {
        #pragma unroll
        for (int cb = 0; cb < 8; ++cb) {
            f32x4 v = {csum[cb][0], csum[cb][1], csum[cb][2], csum[cb][3]};
            *(f32x4*)&cl[wid * 128 + cb * 16 + g * 4] = v;
        }
    }
    __syncthreads();
    if (tid < 128) {
        float s = cl[tid] + cl[128 + tid] + cl[256 + tid] + cl[384 + tid];
        colsum_part[(size_t)tid * nblocks + blockIdx.x] = s;
    }
}

// K1b: 128 blocks, block k reduces contiguous row k -> invS[k], log2S[k]
__global__ __launch_bounds__(256) void k1b_reduce(
        const float* __restrict__ part, float* __restrict__ invS,
        float* __restrict__ lS, int nb)
{
    __shared__ float lds[4];
    const int k = blockIdx.x;
    const int tid = threadIdx.x, wid = tid >> 6, lane = tid & 63;
    float s = 0.f;
    for (int b = tid; b < nb; b += 256) s += part[(size_t)k * nb + b];
    s += __shfl_xor(s, 1);  s += __shfl_xor(s, 2);  s += __shfl_xor(s, 4);
    s += __shfl_xor(s, 8);  s += __shfl_xor(s, 16); s += __shfl_xor(s, 32);
    if (lane == 0) lds[wid] = s;
    __syncthreads();
    if (tid == 0) {
        float tot = lds[0] + lds[1] + lds[2] + lds[3];
        invS[k] = 1.0f / tot;
        lS[k] = __log2f(tot);
    }
}

// K2: read q back (L3-resident), W-ladder + loss. Lean kernel, max occupancy.
__global__ __launch_bounds__(256) void k2_loss(
        const float* __restrict__ q, const float* __restrict__ invS,
        const float* __restrict__ lS, float* __restrict__ losspart, int nblocks)
{
    __shared__ float lds4[4];
    const int tid = threadIdx.x, wid = tid >> 6, lane = tid & 63;
    const float is0 = invS[lane], is1 = invS[lane + 64];
    const float ls0 = lS[lane],   ls1 = lS[lane + 64];

    float loss = 0.f;
    const int gw = blockIdx.x * 4 + wid;
    const int nw = nblocks * 4;

    for (int r4 = gw * 4; r4 < NROWS; r4 += nw * 4) {
        float qa[4], qb[4];
        #pragma unroll
        for (int i = 0; i < 4; ++i) {
            qa[i] = q[(size_t)(r4 + i) * KC + lane];
            qb[i] = q[(size_t)(r4 + i) * KC + 64 + lane];
        }
        #pragma unroll
        for (int i = 0; i < 4; ++i) {
            float w0 = qa[i] * qa[i] * is0;
            float w1 = qb[i] * qb[i] * is1;
            float Wp = w0 + w1;
            Wp += __shfl_xor(Wp, 1);  Wp += __shfl_xor(Wp, 2);
            Wp += __shfl_xor(Wp, 4);  Wp += __shfl_xor(Wp, 8);
            Wp += __shfl_xor(Wp, 16); Wp += __shfl_xor(Wp, 32);
            float iw = frcp(Wp);
            float lw = __log2f(Wp);
            loss += w0 * iw * (__log2f(qa[i]) - ls0 - lw)
                  + w1 * iw * (__log2f(qb[i]) - ls1 - lw);
        }
    }

    loss += __shfl_xor(loss, 1);  loss += __shfl_xor(loss, 2);
    loss += __shfl_xor(loss, 4);  loss += __shfl_xor(loss, 8);
    loss += __shfl_xor(loss, 16); loss += __shfl_xor(loss, 32);
    if (lane == 0) lds4[wid] = loss;
    __syncthreads();
    if (tid == 0) losspart[blockIdx.x] = lds4[0] + lds4[1] + lds4[2] + lds4[3];
}

// K2b: final loss reduce; convert log2 -> ln
__global__ __launch_bounds__(1024) void k2b_final(
        const float* __restrict__ losspart, int nb, float* __restrict__ out)
{
    __shared__ float lds[16];
    const int tid = threadIdx.x;
    float s = 0.f;
    for (int b = tid; b < nb; b += 1024) s += losspart[b];
    s += __shfl_xor(s, 1);  s += __shfl_xor(s, 2);  s += __shfl_xor(s, 4);
    s += __shfl_xor(s, 8);  s += __shfl_xor(s, 16); s += __shfl_xor(s, 32);
    if ((tid & 63) == 0) lds[tid >> 6] = s;
    __syncthreads();
    if (tid == 0) {
        float tot = 0.f;
        #pragma unroll
        for (int i = 0; i < 16; ++i) tot += lds[i];
        out[0] = (float)((double)tot * 0.6931471805599453 /
                         (double)((size_t)NROWS * KC));
    }
}

extern "C" void kernel_launch(void* const* d_in, const int* in_sizes, int n_in,
                              void* d_out, int out_size, void* d_ws, size_t ws_size,
                              hipStream_t stream)
{
    const float* embeds  = (const float*)d_in[0];
    const float* centers = (const float*)d_in[1];
    float* out  = (float*)d_out;
    float* qbuf = out + 1;
    float* ws   = (float*)d_ws;

    const int GB1 = 512;     // K1: 2 blocks/CU (VGPR ~150), write-BW-bound
    const int GB2 = 2048;    // K2: lean, 8 blocks/CU, full occupancy
    float* colsum_part = ws;                          // 128 * GB1 (transposed)
    float* invS  = ws + (size_t)GB1 * 128;            // 128
    float* lS    = invS + 128;                        // 128
    float* lpart = lS + 128;                          // GB2

    hipLaunchKernelGGL(k1_q_colsum, dim3(GB1), dim3(256), 0, stream,
                       embeds, centers, qbuf, colsum_part, GB1);
    hipLaunchKernelGGL(k1b_reduce, dim3(128), dim3(256), 0, stream,
                       colsum_part, invS, lS, GB1);
    hipLaunchKernelGGL(k2_loss, dim3(GB2), dim3(256), 0, stream,
                       qbuf, invS, lS, lpart, GB2);
    hipLaunchKernelGGL(k2b_final, dim3(1), dim3(1024), 0, stream,
                       lpart, GB2, out);
}

// Round 10
// 97.609 us; speedup vs baseline: 1.1416x; 1.1416x over previous
//
#include <hip/hip_runtime.h>
#include <stdint.h>
#include <stddef.h>

typedef __attribute__((ext_vector_type(8))) short bf16x8;
typedef __attribute__((ext_vector_type(4))) float f32x4;

#define NROWS 400000
#define KC 128
#define DIMS 64
#define NTILES (NROWS / 16)

__device__ __forceinline__ short f2bf(float f) {
    union { float f; uint32_t u; } v; v.f = f;
    uint32_t u = v.u;
    uint32_t r = (u + 0x7FFFu + ((u >> 16) & 1u)) >> 16;  // RNE, finite inputs
    return (short)r;
}

__device__ __forceinline__ float frcp(float x) { return __builtin_amdgcn_rcpf(x); }

// Stage -2*centers bf16 fragments (A-operand) into LDS + center norms into cnLDS.
__device__ __forceinline__ void stage_centers_T(
        const float* __restrict__ centers, bf16x8 (*blds)[2][64],
        float* cnLDS, int wid, int lane, int m, int g)
{
    #pragma unroll
    for (int cb = 0; cb < 8; ++cb) {
        float cacc = 0.f;
        bf16x8 bfr[2];
        #pragma unroll
        for (int h = 0; h < 2; ++h) {
            const float* src = centers + (size_t)(cb * 16 + m) * DIMS + h * 32 + g * 8;
            f32x4 c0 = *(const f32x4*)src;
            f32x4 c1 = *(const f32x4*)(src + 4);
            bf16x8 b;
            #pragma unroll
            for (int j = 0; j < 4; ++j) {
                float f0 = c0[j], f1 = c1[j];
                cacc += f0 * f0 + f1 * f1;
                b[j]     = f2bf(-2.0f * f0);
                b[j + 4] = f2bf(-2.0f * f1);
            }
            bfr[h] = b;
        }
        cacc += __shfl_xor(cacc, 16);
        cacc += __shfl_xor(cacc, 32);
        if (wid == 0) {
            blds[cb][0][lane] = bfr[0];
            blds[cb][1][lane] = bfr[1];
            if (g == 0) cnLDS[cb * 16 + m] = cacc;
        }
    }
    __syncthreads();
}

// K1: column sums of q only (no q write). Transposed MFMA D[k][n]. (R8 proven)
__global__ __launch_bounds__(256) void k1_colsum(
        const float* __restrict__ embeds, const float* __restrict__ centers,
        float* __restrict__ colsum_part, int nblocks)
{
    __shared__ bf16x8 blds[8][2][64];
    __shared__ float cnLDS[128];
    __shared__ float cl[4 * 128];
    const int tid = threadIdx.x, wid = tid >> 6, lane = tid & 63;
    const int m = lane & 15, g = lane >> 4;

    stage_centers_T(centers, blds, cnLDS, wid, lane, m, g);

    f32x4 cnr[8];
    #pragma unroll
    for (int cb = 0; cb < 8; ++cb) cnr[cb] = *(const f32x4*)&cnLDS[cb * 16 + g * 4];

    float csum[8][4];
    #pragma unroll
    for (int cb = 0; cb < 8; ++cb)
        #pragma unroll
        for (int r = 0; r < 4; ++r) csum[cb][r] = 0.f;

    const int gwid = blockIdx.x * 4 + wid;
    const int nw = nblocks * 4;

    int t = gwid;
    f32x4 n0, n1, n2, n3;
    if (t < NTILES) {
        const float* src = embeds + (size_t)(t * 16 + m) * DIMS + g * 8;
        n0 = *(const f32x4*)src;       n1 = *(const f32x4*)(src + 4);
        n2 = *(const f32x4*)(src + 32); n3 = *(const f32x4*)(src + 36);
    }
    for (; t < NTILES; t += nw) {
        f32x4 c0 = n0, c1 = n1, c2 = n2, c3 = n3;
        int tn = t + nw;
        if (tn < NTILES) {
            const float* src = embeds + (size_t)(tn * 16 + m) * DIMS + g * 8;
            n0 = *(const f32x4*)src;       n1 = *(const f32x4*)(src + 4);
            n2 = *(const f32x4*)(src + 32); n3 = *(const f32x4*)(src + 36);
        }
        bf16x8 a0, a1;
        float en = 0.f;
        #pragma unroll
        for (int j = 0; j < 4; ++j) {
            float f0 = c0[j], f1 = c1[j], f2 = c2[j], f3 = c3[j];
            en += f0 * f0 + f1 * f1 + f2 * f2 + f3 * f3;
            a0[j] = f2bf(f0); a0[j + 4] = f2bf(f1);
            a1[j] = f2bf(f2); a1[j + 4] = f2bf(f3);
        }
        en += __shfl_xor(en, 16);
        en += __shfl_xor(en, 32);

        f32x4 acc[8];
        #pragma unroll
        for (int cb = 0; cb < 8; ++cb) {
            f32x4 a;
            #pragma unroll
            for (int r = 0; r < 4; ++r) a[r] = cnr[cb][r] + en;
            a = __builtin_amdgcn_mfma_f32_16x16x32_bf16(blds[cb][0][lane], a0, a, 0, 0, 0);
            a = __builtin_amdgcn_mfma_f32_16x16x32_bf16(blds[cb][1][lane], a1, a, 0, 0, 0);
            acc[cb] = a;
        }

        float rsp = 0.f;
        #pragma unroll
        for (int cb = 0; cb < 8; ++cb)
            #pragma unroll
            for (int r = 0; r < 4; ++r) {
                float dist = frcp(1.0f + fmaxf(acc[cb][r], 0.f));
                acc[cb][r] = dist;
                rsp += dist;
            }
        rsp += __shfl_xor(rsp, 16);
        rsp += __shfl_xor(rsp, 32);
        float invR = frcp(rsp);

        #pragma unroll
        for (int cb = 0; cb < 8; ++cb)
            #pragma unroll
            for (int r = 0; r < 4; ++r) csum[cb][r] += acc[cb][r] * invR;
    }

    #pragma unroll
    for (int cb = 0; cb < 8; ++cb)
        #pragma unroll
        for (int r = 0; r < 4; ++r) {
            float v = csum[cb][r];
            v += __shfl_xor(v, 1); v += __shfl_xor(v, 2);
            v += __shfl_xor(v, 4); v += __shfl_xor(v, 8);
            csum[cb][r] = v;
        }
    if (m == 0) {
        #pragma unroll
        for (int cb = 0; cb < 8; ++cb) {
            f32x4 v = {csum[cb][0], csum[cb][1], csum[cb][2], csum[cb][3]};
            *(f32x4*)&cl[wid * 128 + cb * 16 + g * 4] = v;
        }
    }
    __syncthreads();
    if (tid < 128) {
        float s = cl[tid] + cl[128 + tid] + cl[256 + tid] + cl[384 + tid];
        colsum_part[(size_t)tid * nblocks + blockIdx.x] = s;
    }
}

// K1b: 128 blocks, block k reduces contiguous row k -> invS[k], log2S[k]
__global__ __launch_bounds__(256) void k1b_reduce(
        const float* __restrict__ part, float* __restrict__ invS,
        float* __restrict__ lS, int nb)
{
    __shared__ float lds[4];
    const int k = blockIdx.x;
    const int tid = threadIdx.x, wid = tid >> 6, lane = tid & 63;
    float s = 0.f;
    for (int b = tid; b < nb; b += 256) s += part[(size_t)k * nb + b];
    s += __shfl_xor(s, 1);  s += __shfl_xor(s, 2);  s += __shfl_xor(s, 4);
    s += __shfl_xor(s, 8);  s += __shfl_xor(s, 16); s += __shfl_xor(s, 32);
    if (lane == 0) lds[wid] = s;
    __syncthreads();
    if (tid == 0) {
        float tot = lds[0] + lds[1] + lds[2] + lds[3];
        invS[k] = 1.0f / tot;
        lS[k] = __log2f(tot);
    }
}

// K2: recompute sq via transposed MFMA, fused loss, q written via per-wave
// LDS transpose -> fully coalesced dword stores (64 consecutive lanes/instr).
__global__ __launch_bounds__(256) void k2_q_loss(
        const float* __restrict__ embeds, const float* __restrict__ centers,
        const float* __restrict__ invS, const float* __restrict__ lS,
        float* __restrict__ q, float* __restrict__ losspart, int nblocks)
{
    __shared__ bf16x8 blds[8][2][64];
    __shared__ float cnLDS[128], isLDS[128], lsLDS[128];
    __shared__ float lds4[4];
    __shared__ float qt[4][16 * 128];   // per-wave 8KB transpose buffer
    const int tid = threadIdx.x, wid = tid >> 6, lane = tid & 63;
    const int m = lane & 15, g = lane >> 4;

    if (tid < 128) { isLDS[tid] = invS[tid]; lsLDS[tid] = lS[tid]; }
    stage_centers_T(centers, blds, cnLDS, wid, lane, m, g);  // has __syncthreads

    f32x4 cnr[8], isr[8], lsr[8];
    #pragma unroll
    for (int cb = 0; cb < 8; ++cb) {
        cnr[cb] = *(const f32x4*)&cnLDS[cb * 16 + g * 4];
        isr[cb] = *(const f32x4*)&isLDS[cb * 16 + g * 4];
        lsr[cb] = *(const f32x4*)&lsLDS[cb * 16 + g * 4];
    }

    float* myqt = &qt[wid][0];
    float loss = 0.f;
    const int gwid = blockIdx.x * 4 + wid;
    const int nw = nblocks * 4;

    int t = gwid;
    f32x4 n0, n1, n2, n3;
    if (t < NTILES) {
        const float* src = embeds + (size_t)(t * 16 + m) * DIMS + g * 8;
        n0 = *(const f32x4*)src;       n1 = *(const f32x4*)(src + 4);
        n2 = *(const f32x4*)(src + 32); n3 = *(const f32x4*)(src + 36);
    }
    for (; t < NTILES; t += nw) {
        f32x4 c0 = n0, c1 = n1, c2 = n2, c3 = n3;
        int tn = t + nw;
        if (tn < NTILES) {
            const float* src = embeds + (size_t)(tn * 16 + m) * DIMS + g * 8;
            n0 = *(const f32x4*)src;       n1 = *(const f32x4*)(src + 4);
            n2 = *(const f32x4*)(src + 32); n3 = *(const f32x4*)(src + 36);
        }
        bf16x8 a0, a1;
        float en = 0.f;
        #pragma unroll
        for (int j = 0; j < 4; ++j) {
            float f0 = c0[j], f1 = c1[j], f2 = c2[j], f3 = c3[j];
            en += f0 * f0 + f1 * f1 + f2 * f2 + f3 * f3;
            a0[j] = f2bf(f0); a0[j + 4] = f2bf(f1);
            a1[j] = f2bf(f2); a1[j + 4] = f2bf(f3);
        }
        en += __shfl_xor(en, 16);
        en += __shfl_xor(en, 32);

        f32x4 acc[8];
        #pragma unroll
        for (int cb = 0; cb < 8; ++cb) {
            f32x4 a;
            #pragma unroll
            for (int r = 0; r < 4; ++r) a[r] = cnr[cb][r] + en;
            a = __builtin_amdgcn_mfma_f32_16x16x32_bf16(blds[cb][0][lane], a0, a, 0, 0, 0);
            a = __builtin_amdgcn_mfma_f32_16x16x32_bf16(blds[cb][1][lane], a1, a, 0, 0, 0);
            acc[cb] = a;
        }

        float rsp = 0.f;
        #pragma unroll
        for (int cb = 0; cb < 8; ++cb)
            #pragma unroll
            for (int r = 0; r < 4; ++r) {
                float dist = frcp(1.0f + fmaxf(acc[cb][r], 0.f));
                acc[cb][r] = dist;
                rsp += dist;
            }
        rsp += __shfl_xor(rsp, 16);
        rsp += __shfl_xor(rsp, 32);
        float invR = frcp(rsp);

        // qv: accumulate W, stash into per-wave LDS (swizzled) for coalesced store
        float Wp = 0.f;
        #pragma unroll
        for (int cb = 0; cb < 8; ++cb) {
            f32x4 qv4;
            #pragma unroll
            for (int r = 0; r < 4; ++r) {
                float qv = acc[cb][r] * invR;
                acc[cb][r] = qv;
                qv4[r] = qv;
                Wp += qv * qv * isr[cb][r];
            }
            const int col = (cb * 16 + g * 4) ^ ((m & 7) << 2);   // XOR swizzle
            *(f32x4*)&myqt[m * 128 + col] = qv4;                  // ds_write_b128
        }
        Wp += __shfl_xor(Wp, 16);
        Wp += __shfl_xor(Wp, 32);
        float iw = frcp(Wp);
        float lw = __log2f(Wp);

        #pragma unroll
        for (int cb = 0; cb < 8; ++cb)
            #pragma unroll
            for (int r = 0; r < 4; ++r) {
                float qv = acc[cb][r];
                float w = qv * qv * isr[cb][r];
                loss += w * iw * (__log2f(qv) - lsr[cb][r] - lw);
            }

        // coalesced q store: lane -> col lane, col lane+64; rows 0..15
        float* qbase = q + (size_t)t * 16 * KC + lane;
        #pragma unroll
        for (int ro = 0; ro < 16; ++ro) {
            const int sw = (ro & 7) << 2;
            float v0 = myqt[ro * 128 + (lane ^ sw)];
            float v1 = myqt[ro * 128 + ((lane + 64) ^ sw)];
            qbase[ro * KC]      = v0;
            qbase[ro * KC + 64] = v1;
        }
    }

    loss += __shfl_xor(loss, 1);  loss += __shfl_xor(loss, 2);
    loss += __shfl_xor(loss, 4);  loss += __shfl_xor(loss, 8);
    loss += __shfl_xor(loss, 16); loss += __shfl_xor(loss, 32);
    if (lane == 0) lds4[wid] = loss;
    __syncthreads();
    if (tid == 0) losspart[blockIdx.x] = lds4[0] + lds4[1] + lds4[2] + lds4[3];
}

// K2b: final loss reduce; convert log2 -> ln
__global__ __launch_bounds__(1024) void k2b_final(
        const float* __restrict__ losspart, int nb, float* __restrict__ out)
{
    __shared__ float lds[16];
    const int tid = threadIdx.x;
    float s = 0.f;
    for (int b = tid; b < nb; b += 1024) s += losspart[b];
    s += __shfl_xor(s, 1);  s += __shfl_xor(s, 2);  s += __shfl_xor(s, 4);
    s += __shfl_xor(s, 8);  s += __shfl_xor(s, 16); s += __shfl_xor(s, 32);
    if ((tid & 63) == 0) lds[tid >> 6] = s;
    __syncthreads();
    if (tid == 0) {
        float tot = 0.f;
        #pragma unroll
        for (int i = 0; i < 16; ++i) tot += lds[i];
        out[0] = (float)((double)tot * 0.6931471805599453 /
                         (double)((size_t)NROWS * KC));
    }
}

extern "C" void kernel_launch(void* const* d_in, const int* in_sizes, int n_in,
                              void* d_out, int out_size, void* d_ws, size_t ws_size,
                              hipStream_t stream)
{
    const float* embeds  = (const float*)d_in[0];
    const float* centers = (const float*)d_in[1];
    float* out  = (float*)d_out;
    float* qbuf = out + 1;
    float* ws   = (float*)d_ws;

    const int GB1 = 512, GB2 = 512;
    float* colsum_part = ws;                          // 128 * GB1 (transposed)
    float* invS  = ws + (size_t)GB1 * 128;            // 128
    float* lS    = invS + 128;                        // 128
    float* lpart = lS + 128;                          // GB2

    hipLaunchKernelGGL(k1_colsum, dim3(GB1), dim3(256), 0, stream,
                       embeds, centers, colsum_part, GB1);
    hipLaunchKernelGGL(k1b_reduce, dim3(128), dim3(256), 0, stream,
                       colsum_part, invS, lS, GB1);
    hipLaunchKernelGGL(k2_q_loss, dim3(GB2), dim3(256), 0, stream,
                       embeds, centers, invS, lS, qbuf, lpart, GB2);
    hipLaunchKernelGGL(k2b_final, dim3(1), dim3(1024), 0, stream,
                       lpart, GB2, out);
}